// Round 11
// baseline (109.838 us; speedup 1.0000x reference)
//
#include <hip/hip_runtime.h>
#include <math.h>

// Problem dims (fixed): b=2, l=2048, h=8, dh=n=64, g=1.
constexpr int L_ = 2048;
constexpr int H_ = 8;
constexpr int BH_ = 16;        // b*h
constexpr int TSZ = 64;        // tile size
constexpr int NT_ = L_ / TSZ;  // 32 row tiles
constexpr int CHUNK = 4;       // s-tiles per phase-A block (straggler depth)
constexpr int NCHP = NT_ / CHUNK;  // 8 chunks
constexpr float SKIP_THR = -15.f;

typedef __bf16 bf16x8 __attribute__((ext_vector_type(8)));
typedef __bf16 bf16x4 __attribute__((ext_vector_type(4)));
typedef float f32x4 __attribute__((ext_vector_type(4)));

// Workspace (floats): ang|sin|cos|sin*w|cos*w (each BH_*L_) | partials
constexpr size_t ANG_OFF = 0;
constexpr size_t SN_OFF  = ANG_OFF + (size_t)BH_ * L_;
constexpr size_t CS_OFF  = SN_OFF  + (size_t)BH_ * L_;
constexpr size_t SNW_OFF = CS_OFF  + (size_t)BH_ * L_;
constexpr size_t CSW_OFF = SNW_OFF + (size_t)BH_ * L_;
constexpr size_t PART_OFF = CSW_OFF + (size_t)BH_ * L_;  // 32*16*8 slots x 16KB = 67MB

// XOR-swizzle for [64][64] bf16 tiles (row stride 128B): permutes 8-elem
// groups by row so column-slice reads spread across banks (G4).
__device__ __forceinline__ int swz(int row, int d) {
    return row * 64 + ((((d >> 3) ^ (row & 7))) << 3) + (d & 7);
}

// ---- Kernel 1: per-(b,h) cumsum of dt + sin/cos/w tables -------------------
__global__ void scan_kernel(const float* __restrict__ dt, const float* __restrict__ A,
                            float* __restrict__ ws) {
    int bh = blockIdx.x;
    int b = bh >> 3, h = bh & 7;
    int t = threadIdx.x;
    __shared__ float part[256];
    const float* dtp = dt + (size_t)b * L_ * H_ + h;
    float v[8];
    float s = 0.f;
    int l0 = t * 8;
#pragma unroll
    for (int i = 0; i < 8; ++i) { v[i] = dtp[(size_t)(l0 + i) * H_]; s += v[i]; }
    part[t] = s;
    __syncthreads();
#pragma unroll
    for (int off = 1; off < 256; off <<= 1) {
        float add = (t >= off) ? part[t - off] : 0.f;
        __syncthreads();
        part[t] += add;
        __syncthreads();
    }
    float run = (t == 0) ? 0.f : part[t - 1];
    float Ah = A[h];
    size_t base = (size_t)bh * L_ + l0;
#pragma unroll
    for (int i = 0; i < 8; ++i) {
        run += v[i];
        float sn, cs;
        sincosf(run, &sn, &cs);
        float w = 0.5f * (1.f + __expf(Ah * v[i]));
        ws[ANG_OFF + base + i] = run;
        ws[SN_OFF  + base + i] = sn;
        ws[CS_OFF  + base + i] = cs;
        ws[SNW_OFF + base + i] = sn * w;
        ws[CSW_OFF + base + i] = cs * w;
    }
}

// ---- Kernel 2 (phase A): MFMA attention over (rt, bh, s-chunk) -------------
__launch_bounds__(256)
__global__ void attn_kernel(const float* __restrict__ x, const float* __restrict__ A,
                            const float* __restrict__ Bm, const float* __restrict__ Cm,
                            float* __restrict__ ws, float* __restrict__ out) {
    int rt = blockIdx.x, bh = blockIdx.y, cz = blockIdx.z;
    int cz_d = rt / CHUNK;
    if (cz > cz_d) return;
    bool diag = (cz == cz_d);
    int st_lo = cz * CHUNK;
    int b = bh >> 3, h = bh & 7;
    float Ah = A[h];
    int l0 = rt * TSZ;
    const float* angB = ws + ANG_OFF + (size_t)bh * L_;
    const float* snA  = ws + SN_OFF  + (size_t)bh * L_;
    const float* csA  = ws + CS_OFF  + (size_t)bh * L_;
    const float* snwA = ws + SNW_OFF + (size_t)bh * L_;
    const float* cswA = ws + CSW_OFF + (size_t)bh * L_;
    float angL0 = angB[l0];

    auto pred = [&](int st) {
        return Ah * (angL0 - angB[(size_t)st * TSZ + TSZ - 1]) >= SKIP_THR;
    };
    int st_hi = diag ? rt - 1 : st_lo + CHUNK - 1;
    if (!diag && !pred(st_hi)) return;
    // solo: no chunk other than the diag one contributes (window fits)
    bool solo = diag && ((cz_d == 0) || !pred(cz_d * CHUNK - 1));

    // LDS: k/p swizzled [64][64]; vT padded [64][72]
    __shared__ __align__(16) __bf16 lds_k[64 * 64];
    __shared__ __align__(16) __bf16 lds_vt[64 * 72];
    __shared__ __align__(16) __bf16 lds_p[64 * 64];
    __shared__ float angRow[TSZ];
    __shared__ float colfac[TSZ];

    int t = threadIdx.x;
    int w = t >> 6, lane = t & 63, lg = lane >> 4, l15 = lane & 15;

    const float4* B4 = (const float4*)(Bm + (size_t)b * L_ * 64);
    const float4* C4 = (const float4*)(Cm + (size_t)b * L_ * 64);

    int qrow = w * 16 + l15;        // A-frag row
    int rbase = w * 16 + lg * 4;    // D rows = rbase + reg

    // ---- roped Q fragments directly in registers (loop-invariant) ----
    bf16x8 qa0, qa1;
    {
        int ql = l0 + qrow;
        float4 lo0 = C4[(size_t)ql * 16 + lg * 2];
        float4 lo1 = C4[(size_t)ql * 16 + lg * 2 + 1];
        float4 hi0 = C4[(size_t)ql * 16 + lg * 2 + 8];
        float4 hi1 = C4[(size_t)ql * 16 + lg * 2 + 9];
        float sn = snA[ql], cs = csA[ql];
        const float* lo = (const float*)&lo0;   // lo0/lo1 contiguous? use explicit
        float lof[8] = {lo0.x, lo0.y, lo0.z, lo0.w, lo1.x, lo1.y, lo1.z, lo1.w};
        float hif[8] = {hi0.x, hi0.y, hi0.z, hi0.w, hi1.x, hi1.y, hi1.z, hi1.w};
        (void)lo;
#pragma unroll
        for (int j = 0; j < 8; ++j) {
            qa0[j] = (__bf16)(lof[j] * cs - hif[j] * sn);
            qa1[j] = (__bf16)(lof[j] * sn + hif[j] * cs);
        }
    }
    if (t < TSZ) angRow[t] = angB[l0 + t];

    // ---- register prefetch ----
    float4 pBlo[2], pBhi[2], pV[4];
    float pSnw[2], pCsw[2], pAng = 0.f;
    int sq = t >> 4, dqx = t & 15;   // vT staging: 4s x 4d block per thread

    auto prefetch = [&](int s0) {
#pragma unroll
        for (int it = 0; it < 2; ++it) {
            int wi = it * 256 + t;
            int r = wi >> 3, dq = wi & 7;
            int l = s0 + r;
            pBlo[it] = B4[(size_t)l * 16 + dq];
            pBhi[it] = B4[(size_t)l * 16 + dq + 8];
            pSnw[it] = snwA[l];
            pCsw[it] = cswA[l];
        }
        const float4* xv4 = (const float4*)(x + (((size_t)b * L_ + s0) * H_ + h) * 64);
#pragma unroll
        for (int i = 0; i < 4; ++i)
            pV[i] = xv4[(size_t)(sq * 4 + i) * 128 + dqx];  // x s-stride = 128 float4
        if (t < TSZ) pAng = angB[s0 + t];
    };

    auto commit = [&]() {   // regs -> LDS: roped K*w (bf16 swz), V^T (bf16 pad72)
#pragma unroll
        for (int it = 0; it < 2; ++it) {
            int wi = it * 256 + t;
            int r = wi >> 3, dq = wi & 7;
            float sw = pSnw[it], cw = pCsw[it];
            float4 lo = pBlo[it], hi = pBhi[it];
            bf16x4 klo = {(__bf16)(lo.x * cw - hi.x * sw), (__bf16)(lo.y * cw - hi.y * sw),
                          (__bf16)(lo.z * cw - hi.z * sw), (__bf16)(lo.w * cw - hi.w * sw)};
            bf16x4 khi = {(__bf16)(lo.x * sw + hi.x * cw), (__bf16)(lo.y * sw + hi.y * cw),
                          (__bf16)(lo.z * sw + hi.z * cw), (__bf16)(lo.w * sw + hi.w * cw)};
            *(bf16x4*)&lds_k[swz(r, dq * 4)] = klo;
            *(bf16x4*)&lds_k[swz(r, dq * 4 + 32)] = khi;
        }
#pragma unroll
        for (int j = 0; j < 4; ++j) {
            int d = dqx * 4 + j;
            bf16x4 vv = {(__bf16)((const float*)&pV[0])[j], (__bf16)((const float*)&pV[1])[j],
                         (__bf16)((const float*)&pV[2])[j], (__bf16)((const float*)&pV[3])[j]};
            *(bf16x4*)&lds_vt[d * 72 + sq * 4] = vv;
        }
        if (t < TSZ) colfac[t] = __expf(fminf(Ah * (angL0 - pAng), 0.f));
    };

    f32x4 accD[4] = {{0.f, 0.f, 0.f, 0.f}, {0.f, 0.f, 0.f, 0.f},
                     {0.f, 0.f, 0.f, 0.f}, {0.f, 0.f, 0.f, 0.f}};
    f32x4 accO[4] = {{0.f, 0.f, 0.f, 0.f}, {0.f, 0.f, 0.f, 0.f},
                     {0.f, 0.f, 0.f, 0.f}, {0.f, 0.f, 0.f, 0.f}};

    auto s_mfma = [&](f32x4 (&sa)[4]) {
#pragma unroll
        for (int ng = 0; ng < 4; ++ng) {
            int srow = ng * 16 + l15;
            bf16x8 b0 = *(const bf16x8*)&lds_k[swz(srow, lg * 8)];
            bf16x8 b1 = *(const bf16x8*)&lds_k[swz(srow, lg * 8 + 32)];
            f32x4 z = {0.f, 0.f, 0.f, 0.f};
            z = __builtin_amdgcn_mfma_f32_16x16x32_bf16(qa0, b0, z, 0, 0, 0);
            z = __builtin_amdgcn_mfma_f32_16x16x32_bf16(qa1, b1, z, 0, 0, 0);
            sa[ng] = z;
        }
    };

    auto p_write = [&](f32x4 (&sa)[4]) {   // wave-private rows: no barrier needed
#pragma unroll
        for (int ng = 0; ng < 4; ++ng)
#pragma unroll
            for (int reg = 0; reg < 4; ++reg)
                lds_p[swz(rbase + reg, ng * 16 + l15)] = (__bf16)sa[ng][reg];
    };

    auto pv_mfma = [&](f32x4 (&acc)[4]) {
        bf16x8 pa0 = *(const bf16x8*)&lds_p[swz(qrow, lg * 8)];
        bf16x8 pa1 = *(const bf16x8*)&lds_p[swz(qrow, lg * 8 + 32)];
#pragma unroll
        for (int ng = 0; ng < 4; ++ng) {
            int dl = ng * 16 + l15;
            bf16x8 v0 = *(const bf16x8*)&lds_vt[dl * 72 + lg * 8];
            bf16x8 v1 = *(const bf16x8*)&lds_vt[dl * 72 + lg * 8 + 32];
            acc[ng] = __builtin_amdgcn_mfma_f32_16x16x32_bf16(pa0, v0, acc[ng], 0, 0, 0);
            acc[ng] = __builtin_amdgcn_mfma_f32_16x16x32_bf16(pa1, v1, acc[ng], 0, 0, 0);
        }
    };

    int st;
    bool have_next;
    if (diag) {
        prefetch(l0);
        commit();
        st = rt - 1;
        have_next = (st >= st_lo) && pred(st);
        if (have_next) prefetch(st * TSZ);
        __syncthreads();            // k,vT,colfac,angRow visible
        f32x4 sa[4];
        s_mfma(sa);
        float ar[4];
#pragma unroll
        for (int reg = 0; reg < 4; ++reg) ar[reg] = angRow[rbase + reg];
#pragma unroll
        for (int ng = 0; ng < 4; ++ng) {
            int sl = ng * 16 + l15;
            float as = angRow[sl];
#pragma unroll
            for (int reg = 0; reg < 4; ++reg) {
                float dec = (sl <= rbase + reg) ? __expf(Ah * (ar[reg] - as)) : 0.f;
                sa[ng][reg] *= dec;
            }
        }
        p_write(sa);                // wave-local: compiler orders via lgkmcnt
        pv_mfma(accD);
    } else {
        st = st_hi;
        have_next = true;
        prefetch(st * TSZ);
    }

    while (have_next) {
        __syncthreads();            // prev PV reads of lds_vt done (covers 1st iter)
        commit();
        int nst = st - 1;
        bool hn = (nst >= st_lo) && pred(nst);
        if (hn) prefetch(nst * TSZ);
        __syncthreads();            // k,vT,colfac visible
        f32x4 sa[4];
        s_mfma(sa);
#pragma unroll
        for (int ng = 0; ng < 4; ++ng) {
            float cf = colfac[ng * 16 + l15];
#pragma unroll
            for (int reg = 0; reg < 4; ++reg) sa[ng][reg] *= cf;
        }
        p_write(sa);                // wave-local
        pv_mfma(accO);
        st = nst;
        have_next = hn;
    }

    // ---- store: solo diag -> out directly; else partial slot ----
    if (solo) {
        float* op = out + (((size_t)b * L_ + l0) * H_ + h) * 64;
#pragma unroll
        for (int reg = 0; reg < 4; ++reg) {
            int rloc = rbase + reg;
            float rf = __expf(Ah * (angRow[rloc] - angL0));
#pragma unroll
            for (int ng = 0; ng < 4; ++ng)
                op[(size_t)rloc * H_ * 64 + ng * 16 + l15] =
                    accD[ng][reg] + rf * accO[ng][reg];
        }
    } else {
        float* pp = ws + PART_OFF + ((((size_t)rt * BH_ + bh) * NCHP + cz) << 12);
#pragma unroll
        for (int reg = 0; reg < 4; ++reg) {
            int rloc = rbase + reg;
            float rf = __expf(Ah * (angRow[rloc] - angL0));
#pragma unroll
            for (int ng = 0; ng < 4; ++ng)
                pp[(size_t)rloc * 64 + ng * 16 + l15] = accD[ng][reg] + rf * accO[ng][reg];
        }
    }
}

// ---- Kernel 3 (phase B): sum active partials per (rt,bh) when not solo -----
__launch_bounds__(256)
__global__ void reduce_kernel(const float* __restrict__ ws, const float* __restrict__ A,
                              float* __restrict__ out) {
    int rt = blockIdx.x, bh = blockIdx.y;
    int b = bh >> 3, h = bh & 7;
    float Ah = A[h];
    const float* angB = ws + ANG_OFF + (size_t)bh * L_;
    int l0 = rt * TSZ;
    float angL0 = angB[l0];
    int cz_d = rt / CHUNK;
    // bit-identical solo predicate to phase A
    auto pred = [&](int st) {
        return Ah * (angL0 - angB[(size_t)st * TSZ + TSZ - 1]) >= SKIP_THR;
    };
    if ((cz_d == 0) || !pred(cz_d * CHUNK - 1)) return;   // phase A wrote out

    int t = threadIdx.x;
    int r0 = (t >> 4) * 4, c0 = (t & 15) * 4;
    float acc[4][4] = {{0.f}};
    for (int cz = 0; cz <= cz_d; ++cz) {
        if (cz < cz_d) {
            int st_hi = cz * CHUNK + CHUNK - 1;
            if (!pred(st_hi)) continue;
        }
        const float* pp = ws + PART_OFF + ((((size_t)rt * BH_ + bh) * NCHP + cz) << 12);
#pragma unroll
        for (int i = 0; i < 4; ++i) {
            float4 v = *(const float4*)&pp[(size_t)(r0 + i) * 64 + c0];
            acc[i][0] += v.x; acc[i][1] += v.y; acc[i][2] += v.z; acc[i][3] += v.w;
        }
    }
    float* op = out + (((size_t)b * L_ + l0) * H_ + h) * 64;
#pragma unroll
    for (int i = 0; i < 4; ++i)
        *(float4*)&op[(size_t)(r0 + i) * H_ * 64 + c0] =
            make_float4(acc[i][0], acc[i][1], acc[i][2], acc[i][3]);
}

extern "C" void kernel_launch(void* const* d_in, const int* in_sizes, int n_in,
                              void* d_out, int out_size, void* d_ws, size_t ws_size,
                              hipStream_t stream) {
    const float* x  = (const float*)d_in[0];
    const float* dt = (const float*)d_in[1];
    const float* A  = (const float*)d_in[2];
    const float* Bm = (const float*)d_in[3];
    const float* Cm = (const float*)d_in[4];
    float* ws = (float*)d_ws;
    float* out = (float*)d_out;

    scan_kernel<<<BH_, 256, 0, stream>>>(dt, A, ws);
    attn_kernel<<<dim3(NT_, BH_, NCHP), 256, 0, stream>>>(x, A, Bm, Cm, ws, out);
    reduce_kernel<<<dim3(NT_, BH_), 256, 0, stream>>>(ws, A, out);
}

// Round 12
// 100.595 us; speedup vs baseline: 1.0919x; 1.0919x over previous
//
#include <hip/hip_runtime.h>
#include <math.h>

// Problem dims (fixed): b=2, l=2048, h=8, dh=n=64, g=1.
constexpr int L_ = 2048;
constexpr int H_ = 8;
constexpr int BH_ = 16;        // b*h
constexpr int TSZ = 64;        // tile size
constexpr int NT_ = L_ / TSZ;  // 32 row tiles
constexpr int CHUNK = 8;       // s-tiles per phase-A block (R10 value)
constexpr int NCHP = NT_ / CHUNK;  // 4 chunks
constexpr float SKIP_THR = -15.f;

typedef __bf16 bf16x8 __attribute__((ext_vector_type(8)));
typedef __bf16 bf16x4 __attribute__((ext_vector_type(4)));
typedef float f32x4 __attribute__((ext_vector_type(4)));

// Workspace (floats): ang|sin|cos|sin*w|cos*w (each BH_*L_) | partials
constexpr size_t ANG_OFF = 0;
constexpr size_t SN_OFF  = ANG_OFF + (size_t)BH_ * L_;
constexpr size_t CS_OFF  = SN_OFF  + (size_t)BH_ * L_;
constexpr size_t SNW_OFF = CS_OFF  + (size_t)BH_ * L_;
constexpr size_t CSW_OFF = SNW_OFF + (size_t)BH_ * L_;
constexpr size_t PART_OFF = CSW_OFF + (size_t)BH_ * L_;  // 32*16*4 slots x 16KB = 34MB

// XOR-swizzle for [64][64] bf16 tiles (row stride 128B): permutes 8-elem
// groups by row so column-slice reads spread across banks (G4).
__device__ __forceinline__ int swz(int row, int d) {
    return row * 64 + ((((d >> 3) ^ (row & 7))) << 3) + (d & 7);
}

// ---- Kernel 1: per-(b,h) cumsum of dt + sin/cos/w tables -------------------
__global__ void scan_kernel(const float* __restrict__ dt, const float* __restrict__ A,
                            float* __restrict__ ws) {
    int bh = blockIdx.x;
    int b = bh >> 3, h = bh & 7;
    int t = threadIdx.x;
    __shared__ float part[256];
    const float* dtp = dt + (size_t)b * L_ * H_ + h;
    float v[8];
    float s = 0.f;
    int l0 = t * 8;
#pragma unroll
    for (int i = 0; i < 8; ++i) { v[i] = dtp[(size_t)(l0 + i) * H_]; s += v[i]; }
    part[t] = s;
    __syncthreads();
#pragma unroll
    for (int off = 1; off < 256; off <<= 1) {
        float add = (t >= off) ? part[t - off] : 0.f;
        __syncthreads();
        part[t] += add;
        __syncthreads();
    }
    float run = (t == 0) ? 0.f : part[t - 1];
    float Ah = A[h];
    size_t base = (size_t)bh * L_ + l0;
#pragma unroll
    for (int i = 0; i < 8; ++i) {
        run += v[i];
        float sn, cs;
        sincosf(run, &sn, &cs);
        float w = 0.5f * (1.f + __expf(Ah * v[i]));
        ws[ANG_OFF + base + i] = run;
        ws[SN_OFF  + base + i] = sn;
        ws[CS_OFF  + base + i] = cs;
        ws[SNW_OFF + base + i] = sn * w;
        ws[CSW_OFF + base + i] = cs * w;
    }
}

// ---- Kernel 2 (phase A): MFMA attention over (rt, bh, s-chunk) -------------
__launch_bounds__(256)
__global__ void attn_kernel(const float* __restrict__ x, const float* __restrict__ A,
                            const float* __restrict__ Bm, const float* __restrict__ Cm,
                            float* __restrict__ ws, float* __restrict__ out) {
    int rt = blockIdx.x, bh = blockIdx.y, cz = blockIdx.z;
    int cz_d = rt / CHUNK;
    if (cz > cz_d) return;
    bool diag = (cz == cz_d);
    int st_lo = cz * CHUNK;
    int b = bh >> 3, h = bh & 7;
    float Ah = A[h];
    int l0 = rt * TSZ;
    const float* angB = ws + ANG_OFF + (size_t)bh * L_;
    const float* snA  = ws + SN_OFF  + (size_t)bh * L_;
    const float* csA  = ws + CS_OFF  + (size_t)bh * L_;
    const float* snwA = ws + SNW_OFF + (size_t)bh * L_;
    const float* cswA = ws + CSW_OFF + (size_t)bh * L_;
    float angL0 = angB[l0];

    auto pred = [&](int st) {
        return Ah * (angL0 - angB[(size_t)st * TSZ + TSZ - 1]) >= SKIP_THR;
    };
    int st_hi = diag ? rt - 1 : st_lo + CHUNK - 1;
    if (!diag && !pred(st_hi)) return;
    // solo: the decay window fits inside the diag chunk -> write out directly
    bool solo = diag && ((cz_d == 0) || !pred(cz_d * CHUNK - 1));

    // LDS: q/k/p swizzled [64][64]; vT padded [64][72]
    __shared__ __align__(16) __bf16 lds_q[64 * 64];
    __shared__ __align__(16) __bf16 lds_k[64 * 64];
    __shared__ __align__(16) __bf16 lds_vt[64 * 72];
    __shared__ __align__(16) __bf16 lds_p[64 * 64];
    __shared__ float angRow[TSZ];
    __shared__ float colfac[TSZ];

    int t = threadIdx.x;
    int w = t >> 6, lane = t & 63, lg = lane >> 4, l15 = lane & 15;

    const float4* B4 = (const float4*)(Bm + (size_t)b * L_ * 64);
    const float4* C4 = (const float4*)(Cm + (size_t)b * L_ * 64);

    // ---- stage roped Q (bf16, swizzled) — coalesced float4 loads ----
#pragma unroll
    for (int it = 0; it < 2; ++it) {
        int wi = it * 256 + t;
        int r = wi >> 3, dq = wi & 7;
        int l = l0 + r;
        float4 lo = C4[(size_t)l * 16 + dq];
        float4 hi = C4[(size_t)l * 16 + dq + 8];
        float sn = snA[l], cs = csA[l];
        bf16x4 qlo = {(__bf16)(lo.x * cs - hi.x * sn), (__bf16)(lo.y * cs - hi.y * sn),
                      (__bf16)(lo.z * cs - hi.z * sn), (__bf16)(lo.w * cs - hi.w * sn)};
        bf16x4 qhi = {(__bf16)(lo.x * sn + hi.x * cs), (__bf16)(lo.y * sn + hi.y * cs),
                      (__bf16)(lo.z * sn + hi.z * cs), (__bf16)(lo.w * sn + hi.w * cs)};
        *(bf16x4*)&lds_q[swz(r, dq * 4)] = qlo;
        *(bf16x4*)&lds_q[swz(r, dq * 4 + 32)] = qhi;
    }
    if (t < TSZ) angRow[t] = angB[l0 + t];

    // ---- register prefetch ----
    float4 pBlo[2], pBhi[2], pV[4];
    float pSnw[2], pCsw[2], pAng = 0.f;
    int sq = t >> 4, dqx = t & 15;   // vT staging: 4s x 4d block per thread

    auto prefetch = [&](int s0) {
#pragma unroll
        for (int it = 0; it < 2; ++it) {
            int wi = it * 256 + t;
            int r = wi >> 3, dq = wi & 7;
            int l = s0 + r;
            pBlo[it] = B4[(size_t)l * 16 + dq];
            pBhi[it] = B4[(size_t)l * 16 + dq + 8];
            pSnw[it] = snwA[l];
            pCsw[it] = cswA[l];
        }
        const float4* xv4 = (const float4*)(x + (((size_t)b * L_ + s0) * H_ + h) * 64);
#pragma unroll
        for (int i = 0; i < 4; ++i)
            pV[i] = xv4[(size_t)(sq * 4 + i) * 128 + dqx];  // x s-stride = 128 float4
        if (t < TSZ) pAng = angB[s0 + t];
    };

    auto commit = [&]() {   // regs -> LDS: roped K*w (bf16 swz), V^T (bf16 pad72)
#pragma unroll
        for (int it = 0; it < 2; ++it) {
            int wi = it * 256 + t;
            int r = wi >> 3, dq = wi & 7;
            float sw = pSnw[it], cw = pCsw[it];
            float4 lo = pBlo[it], hi = pBhi[it];
            bf16x4 klo = {(__bf16)(lo.x * cw - hi.x * sw), (__bf16)(lo.y * cw - hi.y * sw),
                          (__bf16)(lo.z * cw - hi.z * sw), (__bf16)(lo.w * cw - hi.w * sw)};
            bf16x4 khi = {(__bf16)(lo.x * sw + hi.x * cw), (__bf16)(lo.y * sw + hi.y * cw),
                          (__bf16)(lo.z * sw + hi.z * cw), (__bf16)(lo.w * sw + hi.w * cw)};
            *(bf16x4*)&lds_k[swz(r, dq * 4)] = klo;
            *(bf16x4*)&lds_k[swz(r, dq * 4 + 32)] = khi;
        }
#pragma unroll
        for (int j = 0; j < 4; ++j) {
            int d = dqx * 4 + j;
            bf16x4 vv = {(__bf16)((const float*)&pV[0])[j], (__bf16)((const float*)&pV[1])[j],
                         (__bf16)((const float*)&pV[2])[j], (__bf16)((const float*)&pV[3])[j]};
            *(bf16x4*)&lds_vt[d * 72 + sq * 4] = vv;
        }
        if (t < TSZ) colfac[t] = __expf(fminf(Ah * (angL0 - pAng), 0.f));
    };

    f32x4 accD[4] = {{0.f, 0.f, 0.f, 0.f}, {0.f, 0.f, 0.f, 0.f},
                     {0.f, 0.f, 0.f, 0.f}, {0.f, 0.f, 0.f, 0.f}};
    f32x4 accO[4] = {{0.f, 0.f, 0.f, 0.f}, {0.f, 0.f, 0.f, 0.f},
                     {0.f, 0.f, 0.f, 0.f}, {0.f, 0.f, 0.f, 0.f}};

    int qrow = w * 16 + l15;        // A-frag row
    int rbase = w * 16 + lg * 4;    // D rows = rbase + reg

    auto s_mfma = [&](f32x4 (&sa)[4]) {
        bf16x8 a0 = *(const bf16x8*)&lds_q[swz(qrow, lg * 8)];
        bf16x8 a1 = *(const bf16x8*)&lds_q[swz(qrow, lg * 8 + 32)];
#pragma unroll
        for (int ng = 0; ng < 4; ++ng) {
            int srow = ng * 16 + l15;
            bf16x8 b0 = *(const bf16x8*)&lds_k[swz(srow, lg * 8)];
            bf16x8 b1 = *(const bf16x8*)&lds_k[swz(srow, lg * 8 + 32)];
            f32x4 z = {0.f, 0.f, 0.f, 0.f};
            z = __builtin_amdgcn_mfma_f32_16x16x32_bf16(a0, b0, z, 0, 0, 0);
            z = __builtin_amdgcn_mfma_f32_16x16x32_bf16(a1, b1, z, 0, 0, 0);
            sa[ng] = z;
        }
    };

    auto p_write = [&](f32x4 (&sa)[4]) {   // rows [w*16, w*16+16): wave-private
#pragma unroll
        for (int ng = 0; ng < 4; ++ng)
#pragma unroll
            for (int reg = 0; reg < 4; ++reg)
                lds_p[swz(rbase + reg, ng * 16 + l15)] = (__bf16)sa[ng][reg];
    };

    auto pv_mfma = [&](f32x4 (&acc)[4]) {   // same-wave lds_p reads: lgkmcnt orders
        bf16x8 pa0 = *(const bf16x8*)&lds_p[swz(qrow, lg * 8)];
        bf16x8 pa1 = *(const bf16x8*)&lds_p[swz(qrow, lg * 8 + 32)];
#pragma unroll
        for (int ng = 0; ng < 4; ++ng) {
            int dl = ng * 16 + l15;
            bf16x8 v0 = *(const bf16x8*)&lds_vt[dl * 72 + lg * 8];
            bf16x8 v1 = *(const bf16x8*)&lds_vt[dl * 72 + lg * 8 + 32];
            acc[ng] = __builtin_amdgcn_mfma_f32_16x16x32_bf16(pa0, v0, acc[ng], 0, 0, 0);
            acc[ng] = __builtin_amdgcn_mfma_f32_16x16x32_bf16(pa1, v1, acc[ng], 0, 0, 0);
        }
    };

    int st;
    bool have_next;
    if (diag) {
        prefetch(l0);
        commit();
        st = rt - 1;
        have_next = (st >= st_lo) && pred(st);
        if (have_next) prefetch(st * TSZ);
        __syncthreads();            // q,k,vT,colfac,angRow visible
        f32x4 sa[4];
        s_mfma(sa);
        float ar[4];
#pragma unroll
        for (int reg = 0; reg < 4; ++reg) ar[reg] = angRow[rbase + reg];
#pragma unroll
        for (int ng = 0; ng < 4; ++ng) {
            int sl = ng * 16 + l15;
            float as = angRow[sl];
#pragma unroll
            for (int reg = 0; reg < 4; ++reg) {
                float dec = (sl <= rbase + reg) ? __expf(Ah * (ar[reg] - as)) : 0.f;
                sa[ng][reg] *= dec;
            }
        }
        p_write(sa);                // no barrier: wave-private rows
        pv_mfma(accD);
    } else {
        st = st_hi;
        have_next = true;
        prefetch(st * TSZ);
    }

    while (have_next) {
        __syncthreads();            // prev PV reads of lds_vt/lds_k done
        commit();
        int nst = st - 1;
        bool hn = (nst >= st_lo) && pred(nst);
        if (hn) prefetch(nst * TSZ);
        __syncthreads();            // k,vT,colfac visible
        f32x4 sa[4];
        s_mfma(sa);
#pragma unroll
        for (int ng = 0; ng < 4; ++ng) {
            float cf = colfac[ng * 16 + l15];
#pragma unroll
            for (int reg = 0; reg < 4; ++reg) sa[ng][reg] *= cf;
        }
        p_write(sa);                // no barrier: wave-private rows
        pv_mfma(accO);
        st = nst;
        have_next = hn;
    }

    // ---- store: solo diag -> out directly; else partial slot ----
    if (solo) {
        float* op = out + (((size_t)b * L_ + l0) * H_ + h) * 64;
#pragma unroll
        for (int reg = 0; reg < 4; ++reg) {
            int rloc = rbase + reg;
            float rf = __expf(Ah * (angRow[rloc] - angL0));
#pragma unroll
            for (int ng = 0; ng < 4; ++ng)
                op[(size_t)rloc * H_ * 64 + ng * 16 + l15] =
                    accD[ng][reg] + rf * accO[ng][reg];
        }
    } else {
        float* pp = ws + PART_OFF + ((((size_t)rt * BH_ + bh) * NCHP + cz) << 12);
#pragma unroll
        for (int reg = 0; reg < 4; ++reg) {
            int rloc = rbase + reg;
            float rf = __expf(Ah * (angRow[rloc] - angL0));
#pragma unroll
            for (int ng = 0; ng < 4; ++ng)
                pp[(size_t)rloc * 64 + ng * 16 + l15] = accD[ng][reg] + rf * accO[ng][reg];
        }
    }
}

// ---- Kernel 3 (phase B): sum active partials per (rt,bh) when not solo -----
__launch_bounds__(256)
__global__ void reduce_kernel(const float* __restrict__ ws, const float* __restrict__ A,
                              float* __restrict__ out) {
    int rt = blockIdx.x, bh = blockIdx.y;
    int b = bh >> 3, h = bh & 7;
    float Ah = A[h];
    const float* angB = ws + ANG_OFF + (size_t)bh * L_;
    int l0 = rt * TSZ;
    float angL0 = angB[l0];
    int cz_d = rt / CHUNK;
    auto pred = [&](int st) {   // bit-identical to phase A
        return Ah * (angL0 - angB[(size_t)st * TSZ + TSZ - 1]) >= SKIP_THR;
    };
    if ((cz_d == 0) || !pred(cz_d * CHUNK - 1)) return;   // solo: phase A wrote out

    int t = threadIdx.x;
    int r0 = (t >> 4) * 4, c0 = (t & 15) * 4;
    float acc[4][4] = {{0.f}};
    for (int cz = 0; cz <= cz_d; ++cz) {
        if (cz < cz_d) {
            int st_hi = cz * CHUNK + CHUNK - 1;
            if (!pred(st_hi)) continue;
        }
        const float* pp = ws + PART_OFF + ((((size_t)rt * BH_ + bh) * NCHP + cz) << 12);
#pragma unroll
        for (int i = 0; i < 4; ++i) {
            float4 v = *(const float4*)&pp[(size_t)(r0 + i) * 64 + c0];
            acc[i][0] += v.x; acc[i][1] += v.y; acc[i][2] += v.z; acc[i][3] += v.w;
        }
    }
    float* op = out + (((size_t)b * L_ + l0) * H_ + h) * 64;
#pragma unroll
    for (int i = 0; i < 4; ++i)
        *(float4*)&op[(size_t)(r0 + i) * H_ * 64 + c0] =
            make_float4(acc[i][0], acc[i][1], acc[i][2], acc[i][3]);
}

extern "C" void kernel_launch(void* const* d_in, const int* in_sizes, int n_in,
                              void* d_out, int out_size, void* d_ws, size_t ws_size,
                              hipStream_t stream) {
    const float* x  = (const float*)d_in[0];
    const float* dt = (const float*)d_in[1];
    const float* A  = (const float*)d_in[2];
    const float* Bm = (const float*)d_in[3];
    const float* Cm = (const float*)d_in[4];
    float* ws = (float*)d_ws;
    float* out = (float*)d_out;

    scan_kernel<<<BH_, 256, 0, stream>>>(dt, A, ws);
    attn_kernel<<<dim3(NT_, BH_, NCHP), 256, 0, stream>>>(x, A, Bm, Cm, ws, out);
    reduce_kernel<<<dim3(NT_, BH_), 256, 0, stream>>>(ws, A, out);
}